// Round 10
// baseline (147.548 us; speedup 1.0000x reference)
//
#include <hip/hip_runtime.h>

#define BATCH 512
#define V 6890
#define NJ 24
#define VH (V/2)   // 3445 vertex-pairs

#define NCH 8
#define JREG_BLOCKS (NJ*NCH)            // 192
#define CH_SZ ((V+NCH-1)/NCH)           // 862

// paired-row pk4 layout: 29 float4 rows of length VH.
//   pair p<15 : sd features (2p, 2p+1)            [sd feature j = k*10+l]
//   pair 15   : vt0, vt1
//   pair 16   : vt2, pad(0)
//   pair 17+np: W joints (2np, 2np+1)
// element: pk4[p*VH+vh] = { r0[2vh], r0[2vh+1], r1[2vh], r1[2vh+1] }
#define NPAIR 29
#define N4 (NPAIR*VH)                    // 99905 float4 elements
#define PREP4_BLOCKS ((N4+255)/256)      // 391

// combo grid: [0,192) jreg ; [192,704) batch ; [704,1095) transpose
#define BATCH_FIRST JREG_BLOCKS              // 192
#define TRANS_FIRST (JREG_BLOCKS+BATCH)      // 704
#define COMBO_BLOCKS (TRANS_FIRST+PREP4_BLOCKS) // 1095  (< 2048 = guaranteed co-resident)

// workspace layout (float indices)
// A layout: 256 groups of 2 batches: off = (b>>1)*576 + n*24 + (b&1)*12 + rc
#define A_OFF   0          // BATCH*288 fp32 skinning matrices (pair-grouped)
#define BS_OFF  147456     // BATCH*16 per-batch scalars {b0, b0*beta[1..10], transl[0..2], pad}
#define JP_OFF  155648     // 192*33 jreg partials: [(ch*NJ+j)*33 + m]
#define PK_OFF  162048     // float4-paired pk4 (byte offset 648192, 16B-aligned)

__device__ const int d_par[NJ] = {-1,0,0,0,1,2,3,4,5,6,7,8,9,9,9,12,13,14,16,17,18,19,20,21};

// ---------------- combo: jreg partials + per-batch prep + float4 transpose -----------
// Handoff: jreg blocks release JP via __threadfence + atomicAdd on ctr (= jout[0],
// zeroed by the harness's out-memset). batch blocks acquire-spin until ctr >= 192.
// __launch_bounds__(256,8) caps VGPR<=64 -> 8 blk/CU -> all 1095 blocks co-resident,
// so the spin cannot deadlock. batch-0 later overwrites jout[0] with a normal float
// (bits >= 0x00800000 >> 192), so even late spinners exit, and only after JP is ready.
__global__ __launch_bounds__(256, 8) void combo_k(
    const float* __restrict__ sd, const float* __restrict__ vt,
    const float* __restrict__ W, const float* __restrict__ Jr,
    const float* __restrict__ betas, const float* __restrict__ body_pose,
    const float* __restrict__ go, const float* __restrict__ transl,
    float4* __restrict__ dst4, float* __restrict__ JP,
    float* __restrict__ A, float* __restrict__ bsc, float* __restrict__ jout)
{
  const int bid = blockIdx.x;
  const int t   = threadIdx.x;
  unsigned int* ctr = (unsigned int*)jout;

  __shared__ float red[4*33];
  __shared__ float lb[11];
  __shared__ float lJ[72];
  __shared__ float lR[NJ*9];
  __shared__ float lL[NJ*12];
  __shared__ float lW[NJ*12];

  if (bid < BATCH_FIRST){
    // ================= jreg: (joint j, chunk ch) partial -> JP, then signal =========
    const int r  = bid;                  // r = ch*NJ + j
    const int j  = r % NJ;
    const int v0 = (r / NJ)*CH_SZ;
    const int v1 = (v0+CH_SZ < V) ? v0+CH_SZ : V;
    float acc[33];
#pragma unroll
    for (int m=0;m<33;m++) acc[m]=0.f;
    for (int v=v0+t; v<v1; v+=256){
      const float jr = Jr[j*V+v];
      const float* __restrict__ vp = vt + v*3;
      acc[0] = fmaf(jr, vp[0], acc[0]);
      acc[1] = fmaf(jr, vp[1], acc[1]);
      acc[2] = fmaf(jr, vp[2], acc[2]);
      const float2* __restrict__ sp = (const float2*)(sd + v*30);  // 120B stride, 8B aligned
#pragma unroll
      for (int m=0;m<15;m++){
        const float2 s = sp[m];
        acc[3+2*m]   = fmaf(jr, s.x, acc[3+2*m]);
        acc[3+2*m+1] = fmaf(jr, s.y, acc[3+2*m+1]);
      }
    }
    const int lane = t & 63, wid = t >> 6;
#pragma unroll
    for (int m=0;m<33;m++){
      float x = acc[m];
      x += __shfl_xor(x, 1);
      x += __shfl_xor(x, 2);
      x += __shfl_xor(x, 4);
      x += __shfl_xor(x, 8);
      x += __shfl_xor(x, 16);
      x += __shfl_xor(x, 32);
      if (lane == 0) red[wid*33+m] = x;
    }
    __syncthreads();
    if (t < 33){
      JP[r*33 + t] = red[t] + red[33+t] + red[66+t] + red[99+t];
    }
    __syncthreads();
    if (t == 0){
      __threadfence();                  // release JP
      atomicAdd(ctr, 1u);
    }
  } else if (bid < TRANS_FIRST){
    // ================= batch: spin for JP, then joints/rodrigues/chain/A ============
    const int b = bid - BATCH_FIRST;
    if (t == 0){
      while (atomicAdd(ctr, 0u) < (unsigned)JREG_BLOCKS){
        __builtin_amdgcn_s_sleep(8);
      }
      __threadfence();                  // acquire JP
    }
    __syncthreads();

    if (t < 11) lb[t] = betas[b*11+t];
    __syncthreads();
    const float b0 = lb[0];
    if (t < 72){
      const int j = t/3, k = t-3*j;
      float s = 0.f;
#pragma unroll
      for (int ch=0; ch<NCH; ch++){
        const float* __restrict__ jp = JP + (ch*NJ+j)*33;
        float ss = jp[k];
#pragma unroll
        for (int l=0;l<10;l++) ss = fmaf(lb[1+l], jp[3 + k*10 + l], ss);
        s += ss;
      }
      lJ[t] = b0*s;
    }
    if (t==0) bsc[b*16] = b0;
    if (t>=1 && t<11) bsc[b*16+t] = b0*lb[t];
    if (t<3) bsc[b*16+11+t] = transl[b*3+t];
    if (t < NJ){
      float p0,p1,p2;
      if (t==0){ p0=go[b*3+0]; p1=go[b*3+1]; p2=go[b*3+2]; }
      else { int o=b*69+(t-1)*3; p0=body_pose[o]; p1=body_pose[o+1]; p2=body_pose[o+2]; }
      float a0=p0+1e-8f, a1=p1+1e-8f, a2=p2+1e-8f;
      float angle = sqrtf(a0*a0+a1*a1+a2*a2);
      float inv = 1.0f/angle;
      float rx=p0*inv, ry=p1*inv, rz=p2*inv;
      float sn = sinf(angle), cs = cosf(angle), mc = 1.0f-cs;
      float K[9] = {0.f,-rz,ry, rz,0.f,-rx, -ry,rx,0.f};
      float KK[9];
#pragma unroll
      for (int r=0;r<3;r++)
#pragma unroll
        for (int c=0;c<3;c++)
          KK[r*3+c] = K[r*3+0]*K[0+c] + K[r*3+1]*K[3+c] + K[r*3+2]*K[6+c];
#pragma unroll
      for (int e=0;e<9;e++){
        float ident = (e==0||e==4||e==8)?1.0f:0.0f;
        lR[t*9+e] = ident + sn*K[e] + mc*KK[e];
      }
    }
    __syncthreads();
    for (int idx=t; idx<288; idx+=256){   // 256-thread stride (r4 lesson)
      int j = idx/12, rc = idx-12*j, r = rc>>2, c = rc&3;
      float val;
      if (c<3) val = lR[j*9 + r*3 + c];
      else {
        int p = (j==0) ? 0 : d_par[j];
        val = (j==0) ? lJ[r] : (lJ[j*3+r] - lJ[p*3+r]);
      }
      lL[idx] = val;
    }
    __syncthreads();
    if (t<12) lW[t] = lL[t];
    __syncthreads();
    for (int i=1;i<NJ;i++){
      if (t<12){
        int p = d_par[i];
        int r = t>>2, c = t&3;
        float s = lW[p*12+r*4+0]*lL[i*12+0+c]
                + lW[p*12+r*4+1]*lL[i*12+4+c]
                + lW[p*12+r*4+2]*lL[i*12+8+c];
        if (c==3) s += lW[p*12+r*4+3];
        lW[i*12+t] = s;
      }
      __syncthreads();
    }
    if (t < 72){
      int j=t/3, k=t-3*j;
      jout[b*72+t] = lW[j*12+k*4+3];
    }
    // A (pair-grouped layout) = world with t-col -= R_world @ J
    const int g = b>>1, q = b&1;
    float* __restrict__ Ab = A + g*576 + q*12;
    for (int idx=t; idx<288; idx+=256){   // 256-thread stride (r4 lesson)
      int n=idx/12, rc=idx-12*n, r=rc>>2, c=rc&3;
      float val = lW[n*12+rc];
      if (c==3){
        val -= lW[n*12+r*4+0]*lJ[n*3+0] + lW[n*12+r*4+1]*lJ[n*3+1] + lW[n*12+r*4+2]*lJ[n*3+2];
      }
      Ab[n*24 + rc] = val;
    }
  } else {
    // ================= transpose: float4-paired pk4 =================================
    const int i = (bid - TRANS_FIRST)*256 + t;
    if (i < N4){
      const int p  = i / VH;
      const int vh = i - p*VH;
      const int v0 = 2*vh;
      float4 o;
      if (p < 15){                      // sd rows (2p, 2p+1)
        const float2 a = *(const float2*)(sd + v0*30     + 2*p);
        const float2 b = *(const float2*)(sd + (v0+1)*30 + 2*p);
        o = make_float4(a.x, b.x, a.y, b.y);
      } else if (p == 15){              // vt0, vt1
        const float2 a = *(const float2*)(vt + v0*3);
        const float  b0 = vt[(v0+1)*3], b1 = vt[(v0+1)*3+1];
        o = make_float4(a.x, b0, a.y, b1);
      } else if (p == 16){              // vt2, pad
        o = make_float4(vt[v0*3+2], vt[(v0+1)*3+2], 0.f, 0.f);
      } else {                          // W joints (2(p-17), 2(p-17)+1)
        const int n0 = 2*(p-17);
        const float2 a = *(const float2*)(W + v0*24     + n0);
        const float2 b = *(const float2*)(W + (v0+1)*24 + n0);
        o = make_float4(a.x, b.x, a.y, b.y);
      }
      dst4[i] = o;
    }
  }
}

// ---------------- main LBS: round-9 kernel, unchanged ---------------------------------
__global__ __launch_bounds__(256, 8) void main_k(
    const float* __restrict__ A, const float* __restrict__ bsc,
    const float4* __restrict__ pk4, float* __restrict__ out)
{
  const int vh = blockIdx.x*256 + threadIdx.x;
  if (vh >= VH) return;
  const int bg = blockIdx.y;                 // batch pair (shared by block)
  const float* __restrict__ Ag = A + bg*576;
  const float* __restrict__ bs = bsc + bg*32;

  const float4 vp0 = pk4[15*VH + vh];        // vt0(v0,v1), vt1(v0,v1)
  const float4 vp1 = pk4[16*VH + vh];        // vt2(v0,v1), pad

  float2 vs[2][3];
#pragma unroll
  for (int q=0;q<2;q++){
    const float b0 = bs[q*16];
    vs[q][0] = make_float2(b0*vp0.x, b0*vp0.y);
    vs[q][1] = make_float2(b0*vp0.z, b0*vp0.w);
    vs[q][2] = make_float2(b0*vp1.x, b0*vp1.y);
  }
#pragma unroll
  for (int lp=0; lp<5; lp++){
    const float4 P0 = pk4[(lp   )*VH + vh];  // k=0 rows (2lp, 2lp+1)
    const float4 P1 = pk4[(5+lp )*VH + vh];  // k=1 rows
    const float4 P2 = pk4[(10+lp)*VH + vh];  // k=2 rows
#pragma unroll
    for (int q=0;q<2;q++){
      const float c0 = bs[q*16+1+2*lp];
      const float c1 = bs[q*16+2+2*lp];
      vs[q][0].x = fmaf(c1, P0.z, fmaf(c0, P0.x, vs[q][0].x));
      vs[q][0].y = fmaf(c1, P0.w, fmaf(c0, P0.y, vs[q][0].y));
      vs[q][1].x = fmaf(c1, P1.z, fmaf(c0, P1.x, vs[q][1].x));
      vs[q][1].y = fmaf(c1, P1.w, fmaf(c0, P1.y, vs[q][1].y));
      vs[q][2].x = fmaf(c1, P2.z, fmaf(c0, P2.x, vs[q][2].x));
      vs[q][2].y = fmaf(c1, P2.w, fmaf(c0, P2.y, vs[q][2].y));
    }
  }

  float y[2][6];
#pragma unroll
  for (int q=0;q<2;q++)
#pragma unroll
    for (int i=0;i<6;i++) y[q][i] = 0.f;

#pragma unroll 2
  for (int np=0; np<12; np++){
    const float4 wp = pk4[(17+np)*VH + vh];  // W(2np): xy, W(2np+1): zw
#pragma unroll
    for (int half=0; half<2; half++){
      const int n = 2*np + half;
      const float wx = half ? wp.z : wp.x;
      const float wy = half ? wp.w : wp.y;
#pragma unroll
      for (int q=0;q<2;q++){
        const float* __restrict__ an = Ag + n*24 + q*12;   // block-uniform -> s_load
        float tt;
        tt = fmaf(an[2], vs[q][2].x, fmaf(an[1], vs[q][1].x, fmaf(an[0], vs[q][0].x, an[3])));
        y[q][0] = fmaf(wx, tt, y[q][0]);
        tt = fmaf(an[2], vs[q][2].y, fmaf(an[1], vs[q][1].y, fmaf(an[0], vs[q][0].y, an[3])));
        y[q][1] = fmaf(wy, tt, y[q][1]);
        tt = fmaf(an[6], vs[q][2].x, fmaf(an[5], vs[q][1].x, fmaf(an[4], vs[q][0].x, an[7])));
        y[q][2] = fmaf(wx, tt, y[q][2]);
        tt = fmaf(an[6], vs[q][2].y, fmaf(an[5], vs[q][1].y, fmaf(an[4], vs[q][0].y, an[7])));
        y[q][3] = fmaf(wy, tt, y[q][3]);
        tt = fmaf(an[10], vs[q][2].x, fmaf(an[9], vs[q][1].x, fmaf(an[8], vs[q][0].x, an[11])));
        y[q][4] = fmaf(wx, tt, y[q][4]);
        tt = fmaf(an[10], vs[q][2].y, fmaf(an[9], vs[q][1].y, fmaf(an[8], vs[q][0].y, an[11])));
        y[q][5] = fmaf(wy, tt, y[q][5]);
      }
    }
  }

  const int v0 = 2*vh;
#pragma unroll
  for (int q=0;q<2;q++){
    const float t0 = bs[q*16+11], t1 = bs[q*16+12], t2 = bs[q*16+13];
    const int b = bg*2 + q;
    float2* __restrict__ o2 = (float2*)(out + (b*V + v0)*3);
    o2[0] = make_float2(y[q][0]+t0, y[q][2]+t1);
    o2[1] = make_float2(y[q][4]+t2, y[q][1]+t0);
    o2[2] = make_float2(y[q][3]+t1, y[q][5]+t2);
  }
}

extern "C" void kernel_launch(void* const* d_in, const int* in_sizes, int n_in,
                              void* d_out, int out_size, void* d_ws, size_t ws_size,
                              hipStream_t stream)
{
  const float* betas     = (const float*)d_in[0];
  const float* body_pose = (const float*)d_in[1];
  const float* go        = (const float*)d_in[2];
  const float* transl    = (const float*)d_in[3];
  const float* sdirs     = (const float*)d_in[4];
  const float* vtempl    = (const float*)d_in[5];
  const float* Jr        = (const float*)d_in[6];
  const float* lw        = (const float*)d_in[7];
  float* wsf  = (float*)d_ws;
  float* out  = (float*)d_out;
  float* jout = out + BATCH*V*3;

  hipLaunchKernelGGL(combo_k, dim3(COMBO_BLOCKS), dim3(256), 0, stream,
                     sdirs, vtempl, lw, Jr, betas, body_pose, go, transl,
                     (float4*)(wsf+PK_OFF), wsf+JP_OFF,
                     wsf+A_OFF, wsf+BS_OFF, jout);
  hipLaunchKernelGGL(main_k, dim3((VH+255)/256, BATCH/2), dim3(256), 0, stream,
                     wsf+A_OFF, wsf+BS_OFF, (const float4*)(wsf+PK_OFF), out);
}

// Round 11
// 144.492 us; speedup vs baseline: 1.0212x; 1.0212x over previous
//
#include <hip/hip_runtime.h>

#define BATCH 512
#define V 6890
#define NJ 24
#define VH (V/2)   // 3445 vertex-pairs

#define NCH 8
#define JREG_BLOCKS (NJ*NCH)            // 192
#define CH_SZ ((V+NCH-1)/NCH)           // 862

// paired-row pk4 layout: 29 float4 rows of length VH.
//   pair p<15 : sd features (2p, 2p+1)            [sd feature j = k*10+l]
//   pair 15   : vt0, vt1
//   pair 16   : vt2, pad(0)
//   pair 17+np: W joints (2np, 2np+1)
// element: pk4[p*VH+vh] = { r0[2vh], r0[2vh+1], r1[2vh], r1[2vh+1] }
#define NPAIR 29
#define N4 (NPAIR*VH)                    // 99905 float4 elements
#define PREP4_BLOCKS ((N4+255)/256)      // 391

// combo grid: [0,192) jreg ; [192,704) batch ; [704,1095) transpose
#define BATCH_FIRST JREG_BLOCKS              // 192
#define TRANS_FIRST (JREG_BLOCKS+BATCH)      // 704
#define COMBO_BLOCKS (TRANS_FIRST+PREP4_BLOCKS) // 1095  (< 2048 = guaranteed co-resident)

// workspace layout (float indices)
// A layout: 256 groups of 2 batches: off = (b>>1)*576 + n*24 + (b&1)*12 + rc
#define A_OFF   0          // BATCH*288 fp32 skinning matrices (pair-grouped)
#define BS_OFF  147456     // BATCH*16 per-batch scalars {b0, b0*beta[1..10], transl[0..2], pad}
#define JP_OFF  155648     // 192*33 jreg partials: [(ch*NJ+j)*33 + m]
#define PK_OFF  162048     // float4-paired pk4 (byte offset 648192, 16B-aligned)

__device__ const int d_par[NJ] = {-1,0,0,0,1,2,3,4,5,6,7,8,9,9,9,12,13,14,16,17,18,19,20,21};

// ---------------- combo v2: jreg + batch (overlapped wait) + float4 transpose --------
// Handoff (r10-proven): jreg blocks do __syncthreads -> __threadfence -> atomicAdd(ctr).
// batch blocks run ALL JP-independent work (bsc, rodrigues -> lL rotation columns)
// BEFORE polling, then poll with s_sleep(32) (~0.85us) -> ~1 expected poll iteration,
// >=4x less single-line RMW contention than r10. ctr = jout[0] (harness zeroes out;
// batch-0's later float overwrite has bits >= 0x00800000 >> 192 -> late spinners still
// exit, and only after JP is provably ready -- r10-proven). 1095 blocks all co-resident
// under __launch_bounds__(256,8) -> spin cannot deadlock.
__global__ __launch_bounds__(256, 8) void combo_k(
    const float* __restrict__ sd, const float* __restrict__ vt,
    const float* __restrict__ W, const float* __restrict__ Jr,
    const float* __restrict__ betas, const float* __restrict__ body_pose,
    const float* __restrict__ go, const float* __restrict__ transl,
    float4* __restrict__ dst4, float* __restrict__ JP,
    float* __restrict__ A, float* __restrict__ bsc, float* __restrict__ jout)
{
  const int bid = blockIdx.x;
  const int t   = threadIdx.x;
  unsigned int* ctr = (unsigned int*)jout;

  __shared__ float red[4*33];
  __shared__ float lb[11];
  __shared__ float lJ[72];
  __shared__ float lL[NJ*12];
  __shared__ float lW[NJ*12];

  if (bid < BATCH_FIRST){
    // ================= jreg: (joint j, chunk ch) partial -> JP, then signal =========
    const int r  = bid;                  // r = ch*NJ + j
    const int j  = r % NJ;
    const int v0 = (r / NJ)*CH_SZ;
    const int v1 = (v0+CH_SZ < V) ? v0+CH_SZ : V;
    float acc[33];
#pragma unroll
    for (int m=0;m<33;m++) acc[m]=0.f;
    for (int v=v0+t; v<v1; v+=256){
      const float jr = Jr[j*V+v];
      const float* __restrict__ vp = vt + v*3;
      acc[0] = fmaf(jr, vp[0], acc[0]);
      acc[1] = fmaf(jr, vp[1], acc[1]);
      acc[2] = fmaf(jr, vp[2], acc[2]);
      const float2* __restrict__ sp = (const float2*)(sd + v*30);  // 120B stride, 8B aligned
#pragma unroll
      for (int m=0;m<15;m++){
        const float2 s = sp[m];
        acc[3+2*m]   = fmaf(jr, s.x, acc[3+2*m]);
        acc[3+2*m+1] = fmaf(jr, s.y, acc[3+2*m+1]);
      }
    }
    const int lane = t & 63, wid = t >> 6;
#pragma unroll
    for (int m=0;m<33;m++){
      float x = acc[m];
      x += __shfl_xor(x, 1);
      x += __shfl_xor(x, 2);
      x += __shfl_xor(x, 4);
      x += __shfl_xor(x, 8);
      x += __shfl_xor(x, 16);
      x += __shfl_xor(x, 32);
      if (lane == 0) red[wid*33+m] = x;
    }
    __syncthreads();
    if (t < 33){
      JP[r*33 + t] = red[t] + red[33+t] + red[66+t] + red[99+t];
    }
    __syncthreads();
    if (t == 0){
      __threadfence();                  // release JP
      atomicAdd(ctr, 1u);
    }
  } else if (bid < TRANS_FIRST){
    // ================= batch: JP-independent work FIRST, then poll ==================
    const int b = bid - BATCH_FIRST;
    if (t < 11) lb[t] = betas[b*11+t];
    __syncthreads();
    const float b0 = lb[0];
    // bsc (needs lb/transl only)
    if (t==0) bsc[b*16] = b0;
    if (t>=1 && t<11) bsc[b*16+t] = b0*lb[t];
    if (t<3) bsc[b*16+11+t] = transl[b*3+t];
    // rodrigues -> rotation columns of lL directly (needs pose only)
    if (t < NJ){
      const int j = t;
      float p0,p1,p2;
      if (j==0){ p0=go[b*3+0]; p1=go[b*3+1]; p2=go[b*3+2]; }
      else { int o=b*69+(j-1)*3; p0=body_pose[o]; p1=body_pose[o+1]; p2=body_pose[o+2]; }
      float a0=p0+1e-8f, a1=p1+1e-8f, a2=p2+1e-8f;
      float angle = sqrtf(a0*a0+a1*a1+a2*a2);
      float inv = 1.0f/angle;
      float rx=p0*inv, ry=p1*inv, rz=p2*inv;
      float sn = sinf(angle), cs = cosf(angle), mc = 1.0f-cs;
      float K[9] = {0.f,-rz,ry, rz,0.f,-rx, -ry,rx,0.f};
#pragma unroll
      for (int r=0;r<3;r++)
#pragma unroll
        for (int c=0;c<3;c++){
          float kk = K[r*3+0]*K[0+c] + K[r*3+1]*K[3+c] + K[r*3+2]*K[6+c];
          float ident = (r==c)?1.0f:0.0f;
          lL[j*12 + r*4 + c] = ident + sn*K[r*3+c] + mc*kk;
        }
    }
    // acquire: JP ready? (rodrigues above typically covers jreg's tail -> ~1 poll)
    if (t == 0){
      while (atomicAdd(ctr, 0u) < (unsigned)JREG_BLOCKS){
        __builtin_amdgcn_s_sleep(32);
      }
      __threadfence();                  // acquire JP
    }
    __syncthreads();                    // JP ready + lL rotation cols visible

    // rest joints lJ = b0*(JT + JS.beta), summed over 8 chunk partials
    if (t < 72){
      const int j = t/3, k = t-3*j;
      float s = 0.f;
#pragma unroll
      for (int ch=0; ch<NCH; ch++){
        const float* __restrict__ jp = JP + (ch*NJ+j)*33;
        float ss = jp[k];
#pragma unroll
        for (int l=0;l<10;l++) ss = fmaf(lb[1+l], jp[3 + k*10 + l], ss);
        s += ss;
      }
      lJ[t] = b0*s;
    }
    __syncthreads();
    // translation column of lL
    if (t < 72){
      const int j = t/3, r = t-3*j;
      const int p = d_par[j];
      lL[j*12 + r*4 + 3] = (j==0) ? lJ[r] : (lJ[j*3+r] - lJ[p*3+r]);
    }
    __syncthreads();
    // kinematic chain
    if (t<12) lW[t] = lL[t];
    __syncthreads();
    for (int i=1;i<NJ;i++){
      if (t<12){
        int p = d_par[i];
        int r = t>>2, c = t&3;
        float s = lW[p*12+r*4+0]*lL[i*12+0+c]
                + lW[p*12+r*4+1]*lL[i*12+4+c]
                + lW[p*12+r*4+2]*lL[i*12+8+c];
        if (c==3) s += lW[p*12+r*4+3];
        lW[i*12+t] = s;
      }
      __syncthreads();
    }
    if (t < 72){
      int j=t/3, k=t-3*j;
      jout[b*72+t] = lW[j*12+k*4+3];
    }
    // A (pair-grouped layout) = world with t-col -= R_world @ J
    const int g = b>>1, q = b&1;
    float* __restrict__ Ab = A + g*576 + q*12;
    for (int idx=t; idx<288; idx+=256){   // 256-thread stride (r4 lesson)
      int n=idx/12, rc=idx-12*n, r=rc>>2, c=rc&3;
      float val = lW[n*12+rc];
      if (c==3){
        val -= lW[n*12+r*4+0]*lJ[n*3+0] + lW[n*12+r*4+1]*lJ[n*3+1] + lW[n*12+r*4+2]*lJ[n*3+2];
      }
      Ab[n*24 + rc] = val;
    }
  } else {
    // ================= transpose: float4-paired pk4 =================================
    const int i = (bid - TRANS_FIRST)*256 + t;
    if (i < N4){
      const int p  = i / VH;
      const int vh = i - p*VH;
      const int v0 = 2*vh;
      float4 o;
      if (p < 15){                      // sd rows (2p, 2p+1)
        const float2 a = *(const float2*)(sd + v0*30     + 2*p);
        const float2 b = *(const float2*)(sd + (v0+1)*30 + 2*p);
        o = make_float4(a.x, b.x, a.y, b.y);
      } else if (p == 15){              // vt0, vt1
        const float2 a = *(const float2*)(vt + v0*3);
        const float  b0 = vt[(v0+1)*3], b1 = vt[(v0+1)*3+1];
        o = make_float4(a.x, b0, a.y, b1);
      } else if (p == 16){              // vt2, pad
        o = make_float4(vt[v0*3+2], vt[(v0+1)*3+2], 0.f, 0.f);
      } else {                          // W joints (2(p-17), 2(p-17)+1)
        const int n0 = 2*(p-17);
        const float2 a = *(const float2*)(W + v0*24     + n0);
        const float2 b = *(const float2*)(W + (v0+1)*24 + n0);
        o = make_float4(a.x, b.x, a.y, b.y);
      }
      dst4[i] = o;
    }
  }
}

// ---------------- main LBS: round-9 kernel, byte-identical ----------------------------
__global__ __launch_bounds__(256, 8) void main_k(
    const float* __restrict__ A, const float* __restrict__ bsc,
    const float4* __restrict__ pk4, float* __restrict__ out)
{
  const int vh = blockIdx.x*256 + threadIdx.x;
  if (vh >= VH) return;
  const int bg = blockIdx.y;                 // batch pair (shared by block)
  const float* __restrict__ Ag = A + bg*576;
  const float* __restrict__ bs = bsc + bg*32;

  const float4 vp0 = pk4[15*VH + vh];        // vt0(v0,v1), vt1(v0,v1)
  const float4 vp1 = pk4[16*VH + vh];        // vt2(v0,v1), pad

  float2 vs[2][3];
#pragma unroll
  for (int q=0;q<2;q++){
    const float b0 = bs[q*16];
    vs[q][0] = make_float2(b0*vp0.x, b0*vp0.y);
    vs[q][1] = make_float2(b0*vp0.z, b0*vp0.w);
    vs[q][2] = make_float2(b0*vp1.x, b0*vp1.y);
  }
#pragma unroll
  for (int lp=0; lp<5; lp++){
    const float4 P0 = pk4[(lp   )*VH + vh];  // k=0 rows (2lp, 2lp+1)
    const float4 P1 = pk4[(5+lp )*VH + vh];  // k=1 rows
    const float4 P2 = pk4[(10+lp)*VH + vh];  // k=2 rows
#pragma unroll
    for (int q=0;q<2;q++){
      const float c0 = bs[q*16+1+2*lp];
      const float c1 = bs[q*16+2+2*lp];
      vs[q][0].x = fmaf(c1, P0.z, fmaf(c0, P0.x, vs[q][0].x));
      vs[q][0].y = fmaf(c1, P0.w, fmaf(c0, P0.y, vs[q][0].y));
      vs[q][1].x = fmaf(c1, P1.z, fmaf(c0, P1.x, vs[q][1].x));
      vs[q][1].y = fmaf(c1, P1.w, fmaf(c0, P1.y, vs[q][1].y));
      vs[q][2].x = fmaf(c1, P2.z, fmaf(c0, P2.x, vs[q][2].x));
      vs[q][2].y = fmaf(c1, P2.w, fmaf(c0, P2.y, vs[q][2].y));
    }
  }

  float y[2][6];
#pragma unroll
  for (int q=0;q<2;q++)
#pragma unroll
    for (int i=0;i<6;i++) y[q][i] = 0.f;

#pragma unroll 2
  for (int np=0; np<12; np++){
    const float4 wp = pk4[(17+np)*VH + vh];  // W(2np): xy, W(2np+1): zw
#pragma unroll
    for (int half=0; half<2; half++){
      const int n = 2*np + half;
      const float wx = half ? wp.z : wp.x;
      const float wy = half ? wp.w : wp.y;
#pragma unroll
      for (int q=0;q<2;q++){
        const float* __restrict__ an = Ag + n*24 + q*12;   // block-uniform -> s_load
        float tt;
        tt = fmaf(an[2], vs[q][2].x, fmaf(an[1], vs[q][1].x, fmaf(an[0], vs[q][0].x, an[3])));
        y[q][0] = fmaf(wx, tt, y[q][0]);
        tt = fmaf(an[2], vs[q][2].y, fmaf(an[1], vs[q][1].y, fmaf(an[0], vs[q][0].y, an[3])));
        y[q][1] = fmaf(wy, tt, y[q][1]);
        tt = fmaf(an[6], vs[q][2].x, fmaf(an[5], vs[q][1].x, fmaf(an[4], vs[q][0].x, an[7])));
        y[q][2] = fmaf(wx, tt, y[q][2]);
        tt = fmaf(an[6], vs[q][2].y, fmaf(an[5], vs[q][1].y, fmaf(an[4], vs[q][0].y, an[7])));
        y[q][3] = fmaf(wy, tt, y[q][3]);
        tt = fmaf(an[10], vs[q][2].x, fmaf(an[9], vs[q][1].x, fmaf(an[8], vs[q][0].x, an[11])));
        y[q][4] = fmaf(wx, tt, y[q][4]);
        tt = fmaf(an[10], vs[q][2].y, fmaf(an[9], vs[q][1].y, fmaf(an[8], vs[q][0].y, an[11])));
        y[q][5] = fmaf(wy, tt, y[q][5]);
      }
    }
  }

  const int v0 = 2*vh;
#pragma unroll
  for (int q=0;q<2;q++){
    const float t0 = bs[q*16+11], t1 = bs[q*16+12], t2 = bs[q*16+13];
    const int b = bg*2 + q;
    float2* __restrict__ o2 = (float2*)(out + (b*V + v0)*3);
    o2[0] = make_float2(y[q][0]+t0, y[q][2]+t1);
    o2[1] = make_float2(y[q][4]+t2, y[q][1]+t0);
    o2[2] = make_float2(y[q][3]+t1, y[q][5]+t2);
  }
}

extern "C" void kernel_launch(void* const* d_in, const int* in_sizes, int n_in,
                              void* d_out, int out_size, void* d_ws, size_t ws_size,
                              hipStream_t stream)
{
  const float* betas     = (const float*)d_in[0];
  const float* body_pose = (const float*)d_in[1];
  const float* go        = (const float*)d_in[2];
  const float* transl    = (const float*)d_in[3];
  const float* sdirs     = (const float*)d_in[4];
  const float* vtempl    = (const float*)d_in[5];
  const float* Jr        = (const float*)d_in[6];
  const float* lw        = (const float*)d_in[7];
  float* wsf  = (float*)d_ws;
  float* out  = (float*)d_out;
  float* jout = out + BATCH*V*3;

  hipLaunchKernelGGL(combo_k, dim3(COMBO_BLOCKS), dim3(256), 0, stream,
                     sdirs, vtempl, lw, Jr, betas, body_pose, go, transl,
                     (float4*)(wsf+PK_OFF), wsf+JP_OFF,
                     wsf+A_OFF, wsf+BS_OFF, jout);
  hipLaunchKernelGGL(main_k, dim3((VH+255)/256, BATCH/2), dim3(256), 0, stream,
                     wsf+A_OFF, wsf+BS_OFF, (const float4*)(wsf+PK_OFF), out);
}

// Round 13
// 138.469 us; speedup vs baseline: 1.0656x; 1.0435x over previous
//
#include <hip/hip_runtime.h>

#define BATCH 512
#define V 6890
#define NJ 24
#define VH (V/2)   // 3445 vertex-pairs

#define NCH 8
#define JREG_BLOCKS (NJ*NCH)            // 192
#define CH_SZ ((V+NCH-1)/NCH)           // 862

// paired-row pk4 layout: 29 float4 rows of length VH.
//   pair p<15 : sd features (2p, 2p+1)            [sd feature j = k*10+l]
//   pair 15   : vt0, vt1
//   pair 16   : vt2, pad(0)
//   pair 17+np: W joints (2np, 2np+1)
// element: pk4[p*VH+vh] = { r0[2vh], r0[2vh+1], r1[2vh], r1[2vh+1] }
#define NPAIR 29
#define N4 (NPAIR*VH)                    // 99905 float4 elements
#define PREP4_BLOCKS ((N4+255)/256)      // 391

// workspace layout (float indices)
// A layout: 256 groups of 2 batches: off = (b>>1)*576 + n*24 + (b&1)*12 + rc
#define A_OFF   0          // BATCH*288 fp32 skinning matrices (pair-grouped)
#define BS_OFF  147456     // BATCH*16 per-batch scalars {b0, b0*beta[1..10], transl[0..2], pad}
#define JP_OFF  155648     // 192*33 jreg partials: [(ch*NJ+j)*33 + m]
#define PK_OFF  162048     // float4-paired pk4 (byte offset 648192, 16B-aligned)

__device__ const int d_par[NJ] = {-1,0,0,0,1,2,3,4,5,6,7,8,9,9,9,12,13,14,16,17,18,19,20,21};

// ---------------- fused: float4-paired transpose + chunked joint-regressor -----------
__global__ __launch_bounds__(256) void prepjreg_k(
    const float* __restrict__ sd, const float* __restrict__ vt, const float* __restrict__ W,
    const float* __restrict__ Jr,
    float4* __restrict__ dst4, float* __restrict__ JP)
{
  __shared__ float red[4*33];
  const int bid = blockIdx.x;
  const int t = threadIdx.x;
  if (bid < PREP4_BLOCKS){
    const int i = bid*256 + t;
    if (i >= N4) return;
    const int p  = i / VH;
    const int vh = i - p*VH;
    const int v0 = 2*vh;
    float4 o;
    if (p < 15){                      // sd rows (2p, 2p+1): adjacent -> float2 per vertex
      const float2 a = *(const float2*)(sd + v0*30     + 2*p);
      const float2 b = *(const float2*)(sd + (v0+1)*30 + 2*p);
      o = make_float4(a.x, b.x, a.y, b.y);
    } else if (p == 15){              // vt0, vt1
      const float2 a = *(const float2*)(vt + v0*3);       // v0 even -> 8B aligned
      const float  b0 = vt[(v0+1)*3], b1 = vt[(v0+1)*3+1];
      o = make_float4(a.x, b0, a.y, b1);
    } else if (p == 16){              // vt2, pad
      o = make_float4(vt[v0*3+2], vt[(v0+1)*3+2], 0.f, 0.f);
    } else {                          // W joints (2(p-17), 2(p-17)+1)
      const int n0 = 2*(p-17);
      const float2 a = *(const float2*)(W + v0*24     + n0);
      const float2 b = *(const float2*)(W + (v0+1)*24 + n0);
      o = make_float4(a.x, b.x, a.y, b.y);
    }
    dst4[i] = o;
    return;
  }
  // ---- jreg: (joint j, chunk ch) partial reduction -> JP (reads ORIGINAL layout) ----
  const int r  = bid - PREP4_BLOCKS;   // r = ch*NJ + j
  const int j  = r % NJ;
  const int v0 = (r / NJ)*CH_SZ;
  const int v1 = (v0+CH_SZ < V) ? v0+CH_SZ : V;
  float acc[33];
#pragma unroll
  for (int m=0;m<33;m++) acc[m]=0.f;
  for (int v=v0+t; v<v1; v+=256){
    const float jr = Jr[j*V+v];
    const float* __restrict__ vp = vt + v*3;
    acc[0] = fmaf(jr, vp[0], acc[0]);
    acc[1] = fmaf(jr, vp[1], acc[1]);
    acc[2] = fmaf(jr, vp[2], acc[2]);
    const float2* __restrict__ sp = (const float2*)(sd + v*30);  // 120B stride, 8B aligned
#pragma unroll
    for (int m=0;m<15;m++){
      const float2 s = sp[m];
      acc[3+2*m]   = fmaf(jr, s.x, acc[3+2*m]);
      acc[3+2*m+1] = fmaf(jr, s.y, acc[3+2*m+1]);
    }
  }
  const int lane = t & 63, wid = t >> 6;
#pragma unroll
  for (int m=0;m<33;m++){
    float x = acc[m];
    x += __shfl_xor(x, 1);
    x += __shfl_xor(x, 2);
    x += __shfl_xor(x, 4);
    x += __shfl_xor(x, 8);
    x += __shfl_xor(x, 16);
    x += __shfl_xor(x, 32);
    if (lane == 0) red[wid*33+m] = x;
  }
  __syncthreads();
  if (t < 33){
    JP[r*33 + t] = red[t] + red[33+t] + red[66+t] + red[99+t];
  }
}

// ---------------- per-batch: joints, rodrigues, chain, A (pair-grouped), J_out -------
__global__ __launch_bounds__(64) void batch_k(
    const float* __restrict__ betas, const float* __restrict__ body_pose,
    const float* __restrict__ go, const float* __restrict__ transl,
    const float* __restrict__ JP,
    float* __restrict__ A, float* __restrict__ bsc, float* __restrict__ jout)
{
  const int b = blockIdx.x;
  const int t = threadIdx.x;
  __shared__ float lb[11];
  __shared__ float lJ[72];
  __shared__ float lR[NJ*9];
  __shared__ float lL[NJ*12];
  __shared__ float lW[NJ*12];
  if (t < 11) lb[t] = betas[b*11+t];
  __syncthreads();
  const float b0 = lb[0];
  for (int idx=t; idx<72; idx+=64){
    const int j = idx/3, k = idx-3*j;
    float s = 0.f;
#pragma unroll
    for (int ch=0; ch<NCH; ch++){
      const float* __restrict__ jp = JP + (ch*NJ+j)*33;
      float ss = jp[k];
#pragma unroll
      for (int l=0;l<10;l++) ss = fmaf(lb[1+l], jp[3 + k*10 + l], ss);
      s += ss;
    }
    lJ[idx] = b0*s;
  }
  if (t==0) bsc[b*16] = b0;
  if (t>=1 && t<11) bsc[b*16+t] = b0*lb[t];
  if (t<3) bsc[b*16+11+t] = transl[b*3+t];
  if (t < NJ){
    float p0,p1,p2;
    if (t==0){ p0=go[b*3+0]; p1=go[b*3+1]; p2=go[b*3+2]; }
    else { int o=b*69+(t-1)*3; p0=body_pose[o]; p1=body_pose[o+1]; p2=body_pose[o+2]; }
    float a0=p0+1e-8f, a1=p1+1e-8f, a2=p2+1e-8f;
    float angle = sqrtf(a0*a0+a1*a1+a2*a2);
    float inv = 1.0f/angle;
    float rx=p0*inv, ry=p1*inv, rz=p2*inv;
    float sn = sinf(angle), cs = cosf(angle), mc = 1.0f-cs;
    float K[9] = {0.f,-rz,ry, rz,0.f,-rx, -ry,rx,0.f};
    float KK[9];
    #pragma unroll
    for (int r=0;r<3;r++)
      #pragma unroll
      for (int c=0;c<3;c++)
        KK[r*3+c] = K[r*3+0]*K[0+c] + K[r*3+1]*K[3+c] + K[r*3+2]*K[6+c];
    #pragma unroll
    for (int e=0;e<9;e++){
      float ident = (e==0||e==4||e==8)?1.0f:0.0f;
      lR[t*9+e] = ident + sn*K[e] + mc*KK[e];
    }
  }
  __syncthreads();
  for (int idx=t; idx<288; idx+=64){
    int j = idx/12, rc = idx-12*j, r = rc>>2, c = rc&3;
    float val;
    if (c<3) val = lR[j*9 + r*3 + c];
    else {
      int p = (j==0) ? 0 : d_par[j];
      val = (j==0) ? lJ[r] : (lJ[j*3+r] - lJ[p*3+r]);
    }
    lL[idx] = val;
  }
  __syncthreads();
  if (t<12) lW[t] = lL[t];
  __syncthreads();
  for (int i=1;i<NJ;i++){
    if (t<12){
      int p = d_par[i];
      int r = t>>2, c = t&3;
      float s = lW[p*12+r*4+0]*lL[i*12+0+c]
              + lW[p*12+r*4+1]*lL[i*12+4+c]
              + lW[p*12+r*4+2]*lL[i*12+8+c];
      if (c==3) s += lW[p*12+r*4+3];
      lW[i*12+t] = s;
    }
    __syncthreads();
  }
  for (int idx=t; idx<72; idx+=64){
    int j=idx/3, k=idx-3*j;
    jout[b*72+idx] = lW[j*12+k*4+3];
  }
  // A (pair-grouped layout) = world with t-col -= R_world @ J
  const int g = b>>1, q = b&1;
  float* __restrict__ Ab = A + g*576 + q*12;
  for (int idx=t; idx<288; idx+=64){
    int n=idx/12, rc=idx-12*n, r=rc>>2, c=rc&3;
    float val = lW[n*12+rc];
    if (c==3){
      val -= lW[n*12+r*4+0]*lJ[n*3+0] + lW[n*12+r*4+1]*lJ[n*3+1] + lW[n*12+r*4+2]*lJ[n*3+2];
    }
    Ab[n*24 + rc] = val;
  }
}

// ---------------- main LBS: round-3 shape, float4-paired pk (29 loads, was 57) -------
__global__ __launch_bounds__(256, 8) void main_k(
    const float* __restrict__ A, const float* __restrict__ bsc,
    const float4* __restrict__ pk4, float* __restrict__ out)
{
  const int vh = blockIdx.x*256 + threadIdx.x;
  if (vh >= VH) return;
  const int bg = blockIdx.y;                 // batch pair (shared by block)
  const float* __restrict__ Ag = A + bg*576;
  const float* __restrict__ bs = bsc + bg*32;

  const float4 vp0 = pk4[15*VH + vh];        // vt0(v0,v1), vt1(v0,v1)
  const float4 vp1 = pk4[16*VH + vh];        // vt2(v0,v1), pad

  float2 vs[2][3];
#pragma unroll
  for (int q=0;q<2;q++){
    const float b0 = bs[q*16];
    vs[q][0] = make_float2(b0*vp0.x, b0*vp0.y);
    vs[q][1] = make_float2(b0*vp0.z, b0*vp0.w);
    vs[q][2] = make_float2(b0*vp1.x, b0*vp1.y);
  }
#pragma unroll
  for (int lp=0; lp<5; lp++){
    const float4 P0 = pk4[(lp   )*VH + vh];  // k=0 rows (2lp, 2lp+1)
    const float4 P1 = pk4[(5+lp )*VH + vh];  // k=1 rows
    const float4 P2 = pk4[(10+lp)*VH + vh];  // k=2 rows
#pragma unroll
    for (int q=0;q<2;q++){
      const float c0 = bs[q*16+1+2*lp];
      const float c1 = bs[q*16+2+2*lp];
      vs[q][0].x = fmaf(c1, P0.z, fmaf(c0, P0.x, vs[q][0].x));
      vs[q][0].y = fmaf(c1, P0.w, fmaf(c0, P0.y, vs[q][0].y));
      vs[q][1].x = fmaf(c1, P1.z, fmaf(c0, P1.x, vs[q][1].x));
      vs[q][1].y = fmaf(c1, P1.w, fmaf(c0, P1.y, vs[q][1].y));
      vs[q][2].x = fmaf(c1, P2.z, fmaf(c0, P2.x, vs[q][2].x));
      vs[q][2].y = fmaf(c1, P2.w, fmaf(c0, P2.y, vs[q][2].y));
    }
  }

  float y[2][6];
#pragma unroll
  for (int q=0;q<2;q++)
#pragma unroll
    for (int i=0;i<6;i++) y[q][i] = 0.f;

#pragma unroll 2
  for (int np=0; np<12; np++){
    const float4 wp = pk4[(17+np)*VH + vh];  // W(2np): xy, W(2np+1): zw
#pragma unroll
    for (int half=0; half<2; half++){
      const int n = 2*np + half;
      const float wx = half ? wp.z : wp.x;
      const float wy = half ? wp.w : wp.y;
#pragma unroll
      for (int q=0;q<2;q++){
        const float* __restrict__ an = Ag + n*24 + q*12;   // block-uniform -> s_load
        float tt;
        tt = fmaf(an[2], vs[q][2].x, fmaf(an[1], vs[q][1].x, fmaf(an[0], vs[q][0].x, an[3])));
        y[q][0] = fmaf(wx, tt, y[q][0]);
        tt = fmaf(an[2], vs[q][2].y, fmaf(an[1], vs[q][1].y, fmaf(an[0], vs[q][0].y, an[3])));
        y[q][1] = fmaf(wy, tt, y[q][1]);
        tt = fmaf(an[6], vs[q][2].x, fmaf(an[5], vs[q][1].x, fmaf(an[4], vs[q][0].x, an[7])));
        y[q][2] = fmaf(wx, tt, y[q][2]);
        tt = fmaf(an[6], vs[q][2].y, fmaf(an[5], vs[q][1].y, fmaf(an[4], vs[q][0].y, an[7])));
        y[q][3] = fmaf(wy, tt, y[q][3]);
        tt = fmaf(an[10], vs[q][2].x, fmaf(an[9], vs[q][1].x, fmaf(an[8], vs[q][0].x, an[11])));
        y[q][4] = fmaf(wx, tt, y[q][4]);
        tt = fmaf(an[10], vs[q][2].y, fmaf(an[9], vs[q][1].y, fmaf(an[8], vs[q][0].y, an[11])));
        y[q][5] = fmaf(wy, tt, y[q][5]);
      }
    }
  }

  const int v0 = 2*vh;
#pragma unroll
  for (int q=0;q<2;q++){
    const float t0 = bs[q*16+11], t1 = bs[q*16+12], t2 = bs[q*16+13];
    const int b = bg*2 + q;
    float2* __restrict__ o2 = (float2*)(out + (b*V + v0)*3);
    o2[0] = make_float2(y[q][0]+t0, y[q][2]+t1);
    o2[1] = make_float2(y[q][4]+t2, y[q][1]+t0);
    o2[2] = make_float2(y[q][3]+t1, y[q][5]+t2);
  }
}

extern "C" void kernel_launch(void* const* d_in, const int* in_sizes, int n_in,
                              void* d_out, int out_size, void* d_ws, size_t ws_size,
                              hipStream_t stream)
{
  const float* betas     = (const float*)d_in[0];
  const float* body_pose = (const float*)d_in[1];
  const float* go        = (const float*)d_in[2];
  const float* transl    = (const float*)d_in[3];
  const float* sdirs     = (const float*)d_in[4];
  const float* vtempl    = (const float*)d_in[5];
  const float* Jr        = (const float*)d_in[6];
  const float* lw        = (const float*)d_in[7];
  float* wsf = (float*)d_ws;
  float* out = (float*)d_out;

  hipLaunchKernelGGL(prepjreg_k, dim3(PREP4_BLOCKS + JREG_BLOCKS), dim3(256), 0, stream,
                     sdirs, vtempl, lw, Jr, (float4*)(wsf+PK_OFF), wsf+JP_OFF);
  hipLaunchKernelGGL(batch_k, dim3(BATCH), dim3(64), 0, stream,
                     betas, body_pose, go, transl, wsf+JP_OFF,
                     wsf+A_OFF, wsf+BS_OFF, out + BATCH*V*3);
  hipLaunchKernelGGL(main_k, dim3((VH+255)/256, BATCH/2), dim3(256), 0, stream,
                     wsf+A_OFF, wsf+BS_OFF, (const float4*)(wsf+PK_OFF), out);
}